// Round 4
// baseline (323.715 us; speedup 1.0000x reference)
//
#include <hip/hip_runtime.h>
#include <hip/hip_bf16.h>
#include <hip/hip_fp16.h>
#include <cstdint>

#define N_NODES 100000
#define N_EDGES 1600000
#define FDIM 64
#define NPAIRS 200000
#define NB 391          // dst buckets: ceil(100000/256)
#define BCAP 4864       // bucket fill capacity (avg 4092, +12 sigma)
#define SSTR 5632       // bucket region stride (>= BCAP + 256*3 row padding)
#define EPB 6250        // edges per hist/scatter block (256 blocks)
#define WINSHIFT 14     // src window = 16384 nodes = 2MB of xh
#define NWIN 7          // ceil(100000/16384)

typedef __attribute__((ext_vector_type(8))) _Float16 half8;
typedef __attribute__((ext_vector_type(8))) unsigned short ushort8;
typedef __attribute__((ext_vector_type(4))) float floatx4;

// K0 (fused hist): xh = fp16(x) for all 6250 blocks; blocks < 256 also
// LDS-histogram dst -> matrix[block][bucket].
__global__ void __launch_bounds__(256) k0_fused(const float4* __restrict__ x4,
        __half* __restrict__ xh, const int* __restrict__ dst,
        int* __restrict__ matrix, int* __restrict__ ovfCnt) {
    __shared__ int hist[NB];
    int blk = blockIdx.x, tid = threadIdx.x;
    int i = blk * 256 + tid;                 // exactly 1.6M threads
    if (i == 0) ovfCnt[0] = 0;
    float4 v = x4[i];
    ushort4 o;
    o.x = __half_as_ushort(__float2half(v.x));
    o.y = __half_as_ushort(__float2half(v.y));
    o.z = __half_as_ushort(__float2half(v.z));
    o.w = __half_as_ushort(__float2half(v.w));
    ((ushort4*)xh)[i] = o;
    if (blk < 256) {
        for (int j = tid; j < NB; j += 256) hist[j] = 0;
        __syncthreads();
        int base = blk * EPB;
        for (int j = tid; j < EPB; j += 256)
            atomicAdd(&hist[dst[base + j] >> 8], 1);
        __syncthreads();
        for (int j = tid; j < NB; j += 256) matrix[blk * NB + j] = hist[j];
    }
}

// P1b: per-bucket exclusive scan over 256 block counts (in-place) + totals.
__global__ void __launch_bounds__(256) p1b_scan(int* __restrict__ matrix,
                                                int* __restrict__ bucketCnt) {
    __shared__ int s[256];
    int b = blockIdx.x, t = threadIdx.x;
    int v = matrix[t * NB + b];
    s[t] = v;
    __syncthreads();
    for (int off = 1; off < 256; off <<= 1) {
        int u = (t >= off) ? s[t - off] : 0;
        __syncthreads();
        s[t] += u;
        __syncthreads();
    }
    matrix[t * NB + b] = s[t] - v;           // exclusive prefix
    if (t == 255) bucketCnt[b] = s[255];
}

// P1c: scatter packed (dlow<<17 | src) into bucket regions (stride SSTR).
__global__ void __launch_bounds__(1024) p1c_scatter(const int* __restrict__ src,
        const int* __restrict__ dst, const int* __restrict__ matrix,
        int* __restrict__ bucketArr, int* __restrict__ ovfCnt,
        int2* __restrict__ ovfList) {
    __shared__ int cur[NB];
    int tid = threadIdx.x, blk = blockIdx.x;
    for (int i = tid; i < NB; i += 1024) cur[i] = matrix[blk * NB + i];
    __syncthreads();
    int base = blk * EPB;
    for (int i = tid; i < EPB; i += 1024) {
        int e = base + i;
        int s = src[e], d = dst[e];
        int b = d >> 8;
        int pos = atomicAdd(&cur[b], 1);
        if (pos < BCAP) {
            bucketArr[(size_t)b * SSTR + pos] = ((d & 255) << 17) | s;
        } else {
            int idx = atomicAdd(ovfCnt, 1);
            ovfList[idx] = make_int2(d, s);
        }
    }
}

// P2: per-bucket fine counting sort IN-PLACE; then per-row ascending src
// sort (insertion, rows avg 16) + per-window degree counts packed as bytes
// (wdeg) so k2 can sweep src-windows with no comparisons.
__global__ void __launch_bounds__(256) p2_build(int* __restrict__ bucketArr,
        const int* __restrict__ bucketCnt, int* __restrict__ rowptr,
        int* __restrict__ deg, uint2* __restrict__ wdeg) {
    __shared__ int ebuf[BCAP];               // 19.5 KB
    __shared__ int hist[256], sc[256], cur[256];
    int b = blockIdx.x, t = threadIdx.x;
    int cnt = bucketCnt[b];
    if (cnt > BCAP) cnt = BCAP;
    int* arr = bucketArr + (size_t)b * SSTR;
    hist[t] = 0;
    __syncthreads();
    for (int i = t; i < cnt; i += 256) {
        int e = arr[i];
        ebuf[i] = e;
        atomicAdd(&hist[(e >> 17) & 255], 1);
    }
    __syncthreads();
    int h = hist[t];
    int pc = (h + 3) & ~3;                   // pad row to 4 ints
    sc[t] = pc;
    __syncthreads();
    for (int off = 1; off < 256; off <<= 1) {
        int u = (t >= off) ? sc[t - off] : 0;
        __syncthreads();
        sc[t] += u;
        __syncthreads();
    }
    int rbase = sc[t] - pc;                  // exclusive padded prefix
    cur[t] = rbase;
    int n = (b << 8) + t;
    if (n < N_NODES) {
        rowptr[n] = b * SSTR + rbase;
        deg[n] = h;
    }
    __syncthreads();
    for (int i = t; i < cnt; i += 256) {
        int e = ebuf[i];
        int dl = (e >> 17) & 255;
        int pos = atomicAdd(&cur[dl], 1);
        arr[pos] = e & 0x1FFFF;
    }
    __syncthreads();
    // ---- per-row src sort (thread t owns row t; data L2-hot) ----
    for (int i = 1; i < h; ++i) {
        int v = arr[rbase + i];
        int j = i - 1;
        while (j >= 0 && arr[rbase + j] > v) {
            arr[rbase + j + 1] = arr[rbase + j];
            --j;
        }
        arr[rbase + j + 1] = v;
    }
    // ---- per-window counts packed into 7 bytes (deg << 255 always) ----
    unsigned wlo = 0, whi = 0;
    for (int i = 0; i < h; ++i) {
        int wv = arr[rbase + i] >> WINSHIFT;     // 0..6
        if (wv < 4) wlo += 1u << (8 * wv);
        else        whi += 1u << (8 * (wv - 4));
    }
    if (n < N_NODES) {
        uint2 wd; wd.x = wlo; wd.y = whi;
        wdeg[n] = wd;
    }
}

// K2 (R4: phased src-window sweep): 4 threads/node (32B chunks) -> 1563
// blocks = 6252 waves, fully co-resident in ONE cohort. Rows sorted by src;
// all threads sweep the 7 windows (2MB of xh each) in natural lockstep, so
// the instantaneous gather working set ~= one XCD L2 (4MB) instead of the
// whole 12.8MB table. No grid sync needed: drift only degrades hit-rate.
__device__ __forceinline__ void addrow32(float* acc,
        const __half* __restrict__ xh, int s, int fq) {
    const __half* p = xh + (size_t)s * 64 + fq * 16;
    float4 r0 = *(const float4*)p;
    float4 r1 = *(const float4*)(p + 8);
    const __half2* h0 = (const __half2*)&r0;
    const __half2* h1 = (const __half2*)&r1;
#pragma unroll
    for (int j = 0; j < 4; ++j) {
        float2 f = __half22float2(h0[j]);
        acc[2 * j]     += f.x;
        acc[2 * j + 1] += f.y;
    }
#pragma unroll
    for (int j = 0; j < 4; ++j) {
        float2 f = __half22float2(h1[j]);
        acc[8 + 2 * j]     += f.x;
        acc[8 + 2 * j + 1] += f.y;
    }
}

__global__ void __launch_bounds__(256, 8) k2_agg(const __half* __restrict__ xh,
                       __half* __restrict__ h0h, const int* __restrict__ deg,
                       const int* __restrict__ rowptr, const int* __restrict__ csr,
                       const uint2* __restrict__ wdeg,
                       const int* __restrict__ ovfCnt,
                       const int2* __restrict__ ovfList,
                       const float* __restrict__ x) {
    int unit = blockIdx.x * 256 + threadIdx.x;   // 400k = N*4
    if (unit >= N_NODES * 4) return;
    int n = unit >> 2, fq = unit & 3;            // 32B feature chunk
    const __half* selfp = xh + (size_t)n * 64 + fq * 16;
    float4 r0 = *(const float4*)selfp;
    float4 r1 = *(const float4*)(selfp + 8);
    float acc[16];
    {
        const __half2* h0 = (const __half2*)&r0;
        const __half2* h1 = (const __half2*)&r1;
#pragma unroll
        for (int j = 0; j < 4; ++j) {
            float2 f = __half22float2(h0[j]);
            acc[2 * j]     = 2.f * f.x;
            acc[2 * j + 1] = 2.f * f.y;
        }
#pragma unroll
        for (int j = 0; j < 4; ++j) {
            float2 f = __half22float2(h1[j]);
            acc[8 + 2 * j]     = 2.f * f.x;
            acc[8 + 2 * j + 1] = 2.f * f.y;
        }
    }
    int oc = ovfCnt[0];
    if (oc > 0) {                            // correctness-only path
        for (int i = 0; i < oc; ++i) {
            int2 e = ovfList[i];
            if (e.x == n) {
                const float* xr = x + (size_t)e.y * 64 + fq * 16;
#pragma unroll
                for (int j = 0; j < 16; ++j) acc[j] += xr[j];
            }
        }
    }
    const int* row = csr + rowptr[n];
    uint2 wd = wdeg[n];
    int c = 0;
#pragma unroll
    for (int w = 0; w < NWIN; ++w) {
        int cnt = ((w < 4) ? (wd.x >> (8 * w)) : (wd.y >> (8 * (w - 4)))) & 255;
        for (int i = 0; i < cnt; i += 4) {
            int rem = cnt - i;
            // pad slots make row[c+1..3] safe to read; adds are predicated
            int s0 = row[c];
            int s1 = row[c + 1];
            int s2 = row[c + 2];
            int s3 = row[c + 3];
            addrow32(acc, xh, s0, fq);
            if (rem > 1) addrow32(acc, xh, s1, fq);
            if (rem > 2) addrow32(acc, xh, s2, fq);
            if (rem > 3) addrow32(acc, xh, s3, fq);
            c += (rem < 4) ? rem : 4;
        }
    }
    ushort8 lo, hi;
#pragma unroll
    for (int j = 0; j < 8; ++j) lo[j] = __half_as_ushort(__float2half(acc[j]));
#pragma unroll
    for (int j = 0; j < 8; ++j) hi[j] = __half_as_ushort(__float2half(acc[8 + j]));
    __half* op = h0h + (size_t)n * 64 + fq * 16;
    *(ushort8*)op = lo;
    *(ushort8*)(op + 8) = hi;
}

// K3: node MLP via plain fp16 MFMA (16 nodes/wave).
__global__ void __launch_bounds__(256) k3_mfma(const __half* __restrict__ h,
        __half* __restrict__ hh, const float* __restrict__ w1,
        const float* __restrict__ b1, const float* __restrict__ w2,
        const float* __restrict__ b2) {
    __shared__ half8 WF1[512], WF2[512];     // 16 KB
    __shared__ float Tbuf[4 * 16 * 68];      // 17.4 KB
    int tid = threadIdx.x;
    for (int f = tid; f < 512; f += 256) {
        int lane = f & 63, st = f >> 6;
        int t = st & 3, kh = st >> 2;
        int q = lane >> 4, nl = lane & 15;
        int n = t * 16 + nl;
        int K0 = kh * 32 + q * 8;
        half8 hv1, hv2;
#pragma unroll
        for (int j = 0; j < 8; ++j) {
            hv1[j] = (_Float16)w1[(K0 + j) * 64 + n];
            hv2[j] = (_Float16)w2[(K0 + j) * 64 + n];
        }
        WF1[f] = hv1;
        WF2[f] = hv2;
    }
    __syncthreads();
    int lane = tid & 63;
    int q = lane >> 4, p = lane & 15;
    int wtid0 = blockIdx.x * 4 + (tid >> 6);
    int wtid = wtid0 < 6249 ? wtid0 : 6249;
    int n0 = wtid * 16;
    float b1t[4], b2t[4];
#pragma unroll
    for (int t = 0; t < 4; ++t) {
        b1t[t] = b1[t * 16 + p];
        b2t[t] = b2[t * 16 + p];
    }
    const half8* hrow = (const half8*)(h + (size_t)(n0 + p) * 64);
    half8 A0 = hrow[q], A1 = hrow[4 + q];
    floatx4 acc[4];
#pragma unroll
    for (int t = 0; t < 4; ++t) acc[t] = (floatx4){0.f, 0.f, 0.f, 0.f};
#pragma unroll
    for (int t = 0; t < 4; ++t) {
        acc[t] = __builtin_amdgcn_mfma_f32_16x16x32_f16(A0, WF1[t * 64 + lane],
                                                        acc[t], 0, 0, 0);
        acc[t] = __builtin_amdgcn_mfma_f32_16x16x32_f16(A1, WF1[(4 + t) * 64 + lane],
                                                        acc[t], 0, 0, 0);
    }
    float* T = Tbuf + (tid >> 6) * (16 * 68);
#pragma unroll
    for (int t = 0; t < 4; ++t) {
#pragma unroll
        for (int r = 0; r < 4; ++r)
            T[(q * 4 + r) * 68 + t * 16 + p] = fmaxf(acc[t][r] + b1t[t], 0.f);
    }
    const float* Tp = T + p * 68;
    float4 u0 = *(const float4*)(Tp + q * 8);
    float4 u1 = *(const float4*)(Tp + q * 8 + 4);
    float4 u2 = *(const float4*)(Tp + 32 + q * 8);
    float4 u3 = *(const float4*)(Tp + 32 + q * 8 + 4);
    half8 g0, g1;
    g0[0] = (_Float16)u0.x; g0[1] = (_Float16)u0.y;
    g0[2] = (_Float16)u0.z; g0[3] = (_Float16)u0.w;
    g0[4] = (_Float16)u1.x; g0[5] = (_Float16)u1.y;
    g0[6] = (_Float16)u1.z; g0[7] = (_Float16)u1.w;
    g1[0] = (_Float16)u2.x; g1[1] = (_Float16)u2.y;
    g1[2] = (_Float16)u2.z; g1[3] = (_Float16)u2.w;
    g1[4] = (_Float16)u3.x; g1[5] = (_Float16)u3.y;
    g1[6] = (_Float16)u3.z; g1[7] = (_Float16)u3.w;
#pragma unroll
    for (int t = 0; t < 4; ++t) acc[t] = (floatx4){0.f, 0.f, 0.f, 0.f};
#pragma unroll
    for (int t = 0; t < 4; ++t) {
        acc[t] = __builtin_amdgcn_mfma_f32_16x16x32_f16(g0, WF2[t * 64 + lane],
                                                        acc[t], 0, 0, 0);
        acc[t] = __builtin_amdgcn_mfma_f32_16x16x32_f16(g1, WF2[(4 + t) * 64 + lane],
                                                        acc[t], 0, 0, 0);
    }
    if (wtid0 < 6250) {
#pragma unroll
        for (int t = 0; t < 4; ++t) {
#pragma unroll
            for (int r = 0; r < 4; ++r)
                hh[(size_t)(n0 + q * 4 + r) * 64 + t * 16 + p] =
                    __float2half(fmaxf(acc[t][r] + b2t[t], 0.f));
        }
    }
}

// K4: pair decoder, folded weights: feat@dw1 = e1@(Ws+W1) + e2@(Ws+W2)
// + (e1.*e2)@Wp -> 6 sections, 24 MFMA/task. 782 blocks -> 6256 waves,
// exactly 2 tasks/wave.
__global__ void __launch_bounds__(512) k4_pair(const __half* __restrict__ hh,
                        const int* __restrict__ qidx,
                        const float* __restrict__ dw1, const float* __restrict__ db1,
                        const float* __restrict__ dw2, const float* __restrict__ db2,
                        float* __restrict__ out, int numWaves) {
    __shared__ half8 BF[1536];   // [s(6)][t(4)][lane(64)] -> 24 KB
    int tid = threadIdx.x;
    for (int f = tid; f < 1536; f += 512) {
        int lane = f & 63, st = f >> 6;
        int t = st & 3, s = st >> 2;         // s in [0,6)
        int sec = s >> 1, kh = s & 1;
        int q = lane >> 4, nl = lane & 15;
        int n = t * 16 + nl;
        int K0 = kh * 32 + q * 8;
        half8 hv;
#pragma unroll
        for (int j = 0; j < 8; ++j) {
            int k = K0 + j;
            float v;
            if (sec == 0)      v = dw1[k * 64 + n] + dw1[(128 + k) * 64 + n];
            else if (sec == 1) v = dw1[k * 64 + n] + dw1[(192 + k) * 64 + n];
            else               v = dw1[(64 + k) * 64 + n];
            hv[j] = (_Float16)v;
        }
        BF[f] = hv;
    }
    __syncthreads();
    int lane = tid & 63;
    int q = lane >> 4, nl = lane & 15;
    float db1t[4], dw2t[4];
#pragma unroll
    for (int t = 0; t < 4; ++t) {
        db1t[t] = db1[t * 16 + nl];
        dw2t[t] = dw2[t * 16 + nl];
    }
    float db2v = db2[0];
    int wid = (blockIdx.x * 512 + tid) >> 6;
    for (int task = wid; task < NPAIRS / 16; task += numWaves) {
        int p0 = task * 16;
        int i1 = qidx[p0 + nl];
        int i2 = qidx[NPAIRS + p0 + nl];
        const half8* r1 = (const half8*)(hh + (size_t)i1 * 64);
        const half8* r2 = (const half8*)(hh + (size_t)i2 * 64);
        half8 e1a = r1[q],     e1b = r1[4 + q];
        half8 e2a = r2[q],     e2b = r2[4 + q];
        half8 pA = e1a * e2a,  pB = e1b * e2b;    // v_pk_mul_f16
        floatx4 acc[4];
#pragma unroll
        for (int t = 0; t < 4; ++t) acc[t] = (floatx4){0.f, 0.f, 0.f, 0.f};

#define DO_STEP(S, AV)                                                        \
        _Pragma("unroll")                                                     \
        for (int t = 0; t < 4; ++t)                                           \
            acc[t] = __builtin_amdgcn_mfma_f32_16x16x32_f16(                  \
                (AV), BF[((S) * 4 + t) * 64 + lane], acc[t], 0, 0, 0);

        DO_STEP(0, e1a)  // e1 @ (Ws+W1), k 0..31
        DO_STEP(1, e1b)  // e1 @ (Ws+W1), k 32..63
        DO_STEP(2, e2a)  // e2 @ (Ws+W2)
        DO_STEP(3, e2b)
        DO_STEP(4, pA)   // (e1.*e2) @ Wp
        DO_STEP(5, pB)
#undef DO_STEP

        float part[4] = {0.f, 0.f, 0.f, 0.f};
#pragma unroll
        for (int t = 0; t < 4; ++t) {
#pragma unroll
            for (int r = 0; r < 4; ++r)
                part[r] = fmaf(fmaxf(acc[t][r] + db1t[t], 0.f), dw2t[t], part[r]);
        }
#pragma unroll
        for (int off = 1; off < 16; off <<= 1) {
#pragma unroll
            for (int r = 0; r < 4; ++r) part[r] += __shfl_xor(part[r], off, 64);
        }
        if (nl == 0) {
#pragma unroll
            for (int r = 0; r < 4; ++r) out[p0 + q * 4 + r] = part[r] + db2v;
        }
    }
}

extern "C" void kernel_launch(void* const* d_in, const int* in_sizes, int n_in,
                              void* d_out, int out_size, void* d_ws, size_t ws_size,
                              hipStream_t stream) {
    const float* x    = (const float*)d_in[0];   // [N,64]
    const int*   eidx = (const int*)d_in[1];     // [2,E]
    const int*   qidx = (const int*)d_in[3];     // [2,P]
    const float* w1   = (const float*)d_in[4];
    const float* b1   = (const float*)d_in[5];
    const float* w2   = (const float*)d_in[6];
    const float* b2   = (const float*)d_in[7];
    const float* dw1  = (const float*)d_in[8];   // [256,64]
    const float* db1  = (const float*)d_in[9];
    const float* dw2  = (const float*)d_in[10];  // [64]
    const float* db2  = (const float*)d_in[11];  // [1]
    float* out = (float*)d_out;                  // [P]

    // ws layout (48.41 MB total; 16B aligned):
    //   h0h (fp16) @ 0          : 12,800,000 B
    //   xh / hh    @ 12,800,000 : 12,800,000 B
    //   bucketArr  @ 25,600,000 :  8,808,448 B
    //   ovfList    @ 34,408,448 :  8,000,000 B (cap 1M int2; realistic ovf ~0)
    //   wdeg       @ 42,408,448 :    800,000 B (uint2 per node)
    //   rowptr     @ 47,208,448 :    400,000 B
    //   deg        @ 47,608,448 :    400,000 B
    //   matrix     @ 48,008,448 :    400,384 B
    //   bucketCnt  @ 48,408,832 :      1,564 B
    //   ovfCnt     @ 48,410,396 :          4 B
    char* ws = (char*)d_ws;
    __half* h0h       = (__half*)ws;
    __half* xh        = (__half*)(ws + 12800000);
    int*    bucketArr = (int*)(ws + 25600000);
    int2*   ovfList   = (int2*)(ws + 34408448);
    uint2*  wdeg      = (uint2*)(ws + 42408448);
    int*    rowptr    = (int*)(ws + 47208448);
    int*    deg       = (int*)(ws + 47608448);
    int*    matrix    = (int*)(ws + 48008448);
    int*    bucketCnt = (int*)(ws + 48408832);
    int*    ovfCnt    = (int*)(ws + 48410396);

    const int* src = eidx;
    const int* dst = eidx + N_EDGES;

    k0_fused<<<6250, 256, 0, stream>>>((const float4*)x, xh, dst, matrix, ovfCnt);
    p1b_scan<<<NB, 256, 0, stream>>>(matrix, bucketCnt);
    p1c_scatter<<<256, 1024, 0, stream>>>(src, dst, matrix, bucketArr,
                                          ovfCnt, ovfList);
    p2_build<<<NB, 256, 0, stream>>>(bucketArr, bucketCnt, rowptr, deg, wdeg);
    // K2: 1563 blocks x 4 waves = 6252 waves -- fully co-resident cohort
    k2_agg<<<1563, 256, 0, stream>>>(xh, h0h, deg, rowptr, bucketArr, wdeg,
                                     ovfCnt, ovfList, x);
    k3_mfma<<<1563, 256, 0, stream>>>(h0h, xh, w1, b1, w2, b2);
    // K4: 782 blocks x 8 waves = 6256 waves -> exactly 2 tasks/wave
    k4_pair<<<782, 512, 0, stream>>>(xh, qidx, dw1, db1, dw2, db2, out, 6256);
}

// Round 5
// 217.208 us; speedup vs baseline: 1.4903x; 1.4903x over previous
//
#include <hip/hip_runtime.h>
#include <hip/hip_bf16.h>
#include <hip/hip_fp16.h>
#include <cstdint>

#define N_NODES 100000
#define N_EDGES 1600000
#define FDIM 64
#define NPAIRS 200000
#define NB 391          // dst buckets: ceil(100000/256)
#define BCAP 4864       // bucket fill capacity (avg 4092, +12 sigma)
#define SSTR 5632       // bucket region stride (>= BCAP + 256*3 row padding)
#define EPB 6250        // edges per hist/scatter block (256 blocks)

typedef __attribute__((ext_vector_type(8))) _Float16 half8;
typedef __attribute__((ext_vector_type(8))) unsigned short ushort8;
typedef __attribute__((ext_vector_type(4))) float floatx4;

// K0 (fused hist): xh = fp16(x) for all 6250 blocks; blocks < 256 also
// LDS-histogram dst -> matrix[block][bucket].
__global__ void __launch_bounds__(256) k0_fused(const float4* __restrict__ x4,
        __half* __restrict__ xh, const int* __restrict__ dst,
        int* __restrict__ matrix, int* __restrict__ ovfCnt) {
    __shared__ int hist[NB];
    int blk = blockIdx.x, tid = threadIdx.x;
    int i = blk * 256 + tid;                 // exactly 1.6M threads
    if (i == 0) ovfCnt[0] = 0;
    float4 v = x4[i];
    ushort4 o;
    o.x = __half_as_ushort(__float2half(v.x));
    o.y = __half_as_ushort(__float2half(v.y));
    o.z = __half_as_ushort(__float2half(v.z));
    o.w = __half_as_ushort(__float2half(v.w));
    ((ushort4*)xh)[i] = o;
    if (blk < 256) {
        for (int j = tid; j < NB; j += 256) hist[j] = 0;
        __syncthreads();
        int base = blk * EPB;
        for (int j = tid; j < EPB; j += 256)
            atomicAdd(&hist[dst[base + j] >> 8], 1);
        __syncthreads();
        for (int j = tid; j < NB; j += 256) matrix[blk * NB + j] = hist[j];
    }
}

// P1b: per-bucket exclusive scan over 256 block counts (in-place) + totals.
__global__ void __launch_bounds__(256) p1b_scan(int* __restrict__ matrix,
                                                int* __restrict__ bucketCnt) {
    __shared__ int s[256];
    int b = blockIdx.x, t = threadIdx.x;
    int v = matrix[t * NB + b];
    s[t] = v;
    __syncthreads();
    for (int off = 1; off < 256; off <<= 1) {
        int u = (t >= off) ? s[t - off] : 0;
        __syncthreads();
        s[t] += u;
        __syncthreads();
    }
    matrix[t * NB + b] = s[t] - v;           // exclusive prefix
    if (t == 255) bucketCnt[b] = s[255];
}

// P1c: scatter packed (dlow<<17 | src) into bucket regions (stride SSTR).
// 1024 threads/block (4x memory parallelism; slot order within a
// (block,bucket) window is irrelevant, so larger blocks are safe).
// Overflow beyond BCAP: append to ovfList (cap large); k2 replays it.
__global__ void __launch_bounds__(1024) p1c_scatter(const int* __restrict__ src,
        const int* __restrict__ dst, const int* __restrict__ matrix,
        int* __restrict__ bucketArr, int* __restrict__ ovfCnt,
        int2* __restrict__ ovfList) {
    __shared__ int cur[NB];
    int tid = threadIdx.x, blk = blockIdx.x;
    for (int i = tid; i < NB; i += 1024) cur[i] = matrix[blk * NB + i];
    __syncthreads();
    int base = blk * EPB;
    for (int i = tid; i < EPB; i += 1024) {
        int e = base + i;
        int s = src[e], d = dst[e];
        int b = d >> 8;
        int pos = atomicAdd(&cur[b], 1);
        if (pos < BCAP) {
            bucketArr[(size_t)b * SSTR + pos] = ((d & 255) << 17) | s;
        } else {
            int idx = atomicAdd(ovfCnt, 1);
            ovfList[idx] = make_int2(d, s);
        }
    }
}

// P2: per-bucket fine counting sort IN-PLACE.
// (R5: reverted R4's per-row global-memory insertion sort -- it was a
// latency-serial 10x regression, 122us vs ~12us. Slot order within a row
// is irrelevant to correctness.)
__global__ void __launch_bounds__(256) p2_build(int* __restrict__ bucketArr,
        const int* __restrict__ bucketCnt, int* __restrict__ rowptr,
        int* __restrict__ deg) {
    __shared__ int ebuf[BCAP];               // 19.5 KB
    __shared__ int hist[256], sc[256], cur[256];
    int b = blockIdx.x, t = threadIdx.x;
    int cnt = bucketCnt[b];
    if (cnt > BCAP) cnt = BCAP;
    int* arr = bucketArr + (size_t)b * SSTR;
    hist[t] = 0;
    __syncthreads();
    for (int i = t; i < cnt; i += 256) {
        int e = arr[i];
        ebuf[i] = e;
        atomicAdd(&hist[(e >> 17) & 255], 1);
    }
    __syncthreads();
    int h = hist[t];
    int pc = (h + 3) & ~3;                   // pad row to 4 ints
    sc[t] = pc;
    __syncthreads();
    for (int off = 1; off < 256; off <<= 1) {
        int u = (t >= off) ? sc[t - off] : 0;
        __syncthreads();
        sc[t] += u;
        __syncthreads();
    }
    int rbase = sc[t] - pc;                  // exclusive padded prefix
    cur[t] = rbase;
    int n = (b << 8) + t;
    if (n < N_NODES) {
        rowptr[n] = b * SSTR + rbase;
        deg[n] = h;
    }
    __syncthreads();
    for (int i = t; i < cnt; i += 256) {
        int e = ebuf[i];
        int dl = (e >> 17) & 255;
        int pos = atomicAdd(&cur[dl], 1);
        arr[pos] = e & 0x1FFFF;
    }
}

// K2 (16B gathers): thread per (node, 8-half chunk); fq in [0,8).
// 16 neighbors x 16B = 256B outstanding per thread.
__device__ __forceinline__ void addrow16(float4& a0, float4& a1,
        const __half* __restrict__ xh, int s, int fq) {
    float4 raw = *(const float4*)(xh + (size_t)s * 64 + fq * 8);
    __half2 h0 = *(__half2*)&raw.x;
    __half2 h1 = *(__half2*)&raw.y;
    __half2 h2 = *(__half2*)&raw.z;
    __half2 h3 = *(__half2*)&raw.w;
    float2 f0 = __half22float2(h0), f1 = __half22float2(h1);
    float2 f2 = __half22float2(h2), f3 = __half22float2(h3);
    a0.x += f0.x; a0.y += f0.y; a0.z += f1.x; a0.w += f1.y;
    a1.x += f2.x; a1.y += f2.y; a1.z += f3.x; a1.w += f3.y;
}

__global__ void __launch_bounds__(256) k2_agg(const __half* __restrict__ xh,
                       __half* __restrict__ h0h, const int* __restrict__ deg,
                       const int* __restrict__ rowptr, const int* __restrict__ csr,
                       const int* __restrict__ ovfCnt,
                       const int2* __restrict__ ovfList,
                       const float* __restrict__ x) {
    int gid = blockIdx.x * 256 + threadIdx.x;   // 800k = N*8
    int n = gid >> 3, fq = gid & 7;
    int dc = deg[n];
    const int4* srow = (const int4*)(csr + rowptr[n]);
    float4 raw = *(const float4*)(xh + (size_t)n * 64 + fq * 8);
    __half2 h0 = *(__half2*)&raw.x;
    __half2 h1 = *(__half2*)&raw.y;
    __half2 h2 = *(__half2*)&raw.z;
    __half2 h3 = *(__half2*)&raw.w;
    float2 f0 = __half22float2(h0), f1 = __half22float2(h1);
    float2 f2 = __half22float2(h2), f3 = __half22float2(h3);
    float4 a0 = {2.f * f0.x, 2.f * f0.y, 2.f * f1.x, 2.f * f1.y};
    float4 a1 = {2.f * f2.x, 2.f * f2.y, 2.f * f3.x, 2.f * f3.y};
    int oc = ovfCnt[0];
    if (oc > 0) {                            // correctness-only path
        for (int i = 0; i < oc; ++i) {
            int2 e = ovfList[i];
            if (e.x == n) {
                const float* xr = x + (size_t)e.y * 64 + fq * 8;
                a0.x += xr[0]; a0.y += xr[1]; a0.z += xr[2]; a0.w += xr[3];
                a1.x += xr[4]; a1.y += xr[5]; a1.z += xr[6]; a1.w += xr[7];
            }
        }
    }
    for (int i = 0; i < dc; i += 16) {
        int4 s4 = srow[i >> 2];
        int4 s5, s6, s7;
        if (i + 4 < dc)  s5 = srow[(i >> 2) + 1];
        if (i + 8 < dc)  s6 = srow[(i >> 2) + 2];
        if (i + 12 < dc) s7 = srow[(i >> 2) + 3];
        addrow16(a0, a1, xh, s4.x, fq);
        if (i + 1 < dc)  addrow16(a0, a1, xh, s4.y, fq);
        if (i + 2 < dc)  addrow16(a0, a1, xh, s4.z, fq);
        if (i + 3 < dc)  addrow16(a0, a1, xh, s4.w, fq);
        if (i + 4 < dc)  addrow16(a0, a1, xh, s5.x, fq);
        if (i + 5 < dc)  addrow16(a0, a1, xh, s5.y, fq);
        if (i + 6 < dc)  addrow16(a0, a1, xh, s5.z, fq);
        if (i + 7 < dc)  addrow16(a0, a1, xh, s5.w, fq);
        if (i + 8 < dc)  addrow16(a0, a1, xh, s6.x, fq);
        if (i + 9 < dc)  addrow16(a0, a1, xh, s6.y, fq);
        if (i + 10 < dc) addrow16(a0, a1, xh, s6.z, fq);
        if (i + 11 < dc) addrow16(a0, a1, xh, s6.w, fq);
        if (i + 12 < dc) addrow16(a0, a1, xh, s7.x, fq);
        if (i + 13 < dc) addrow16(a0, a1, xh, s7.y, fq);
        if (i + 14 < dc) addrow16(a0, a1, xh, s7.z, fq);
        if (i + 15 < dc) addrow16(a0, a1, xh, s7.w, fq);
    }
    ushort8 st;
    st[0] = __half_as_ushort(__float2half(a0.x));
    st[1] = __half_as_ushort(__float2half(a0.y));
    st[2] = __half_as_ushort(__float2half(a0.z));
    st[3] = __half_as_ushort(__float2half(a0.w));
    st[4] = __half_as_ushort(__float2half(a1.x));
    st[5] = __half_as_ushort(__float2half(a1.y));
    st[6] = __half_as_ushort(__float2half(a1.z));
    st[7] = __half_as_ushort(__float2half(a1.w));
    *(ushort8*)(h0h + (size_t)n * 64 + fq * 8) = st;
}

// K3: node MLP via plain fp16 MFMA (16 nodes/wave).
__global__ void __launch_bounds__(256) k3_mfma(const __half* __restrict__ h,
        __half* __restrict__ hh, const float* __restrict__ w1,
        const float* __restrict__ b1, const float* __restrict__ w2,
        const float* __restrict__ b2) {
    __shared__ half8 WF1[512], WF2[512];     // 16 KB
    __shared__ float Tbuf[4 * 16 * 68];      // 17.4 KB
    int tid = threadIdx.x;
    for (int f = tid; f < 512; f += 256) {
        int lane = f & 63, st = f >> 6;
        int t = st & 3, kh = st >> 2;
        int q = lane >> 4, nl = lane & 15;
        int n = t * 16 + nl;
        int K0 = kh * 32 + q * 8;
        half8 hv1, hv2;
#pragma unroll
        for (int j = 0; j < 8; ++j) {
            hv1[j] = (_Float16)w1[(K0 + j) * 64 + n];
            hv2[j] = (_Float16)w2[(K0 + j) * 64 + n];
        }
        WF1[f] = hv1;
        WF2[f] = hv2;
    }
    __syncthreads();
    int lane = tid & 63;
    int q = lane >> 4, p = lane & 15;
    int wtid0 = blockIdx.x * 4 + (tid >> 6);
    int wtid = wtid0 < 6249 ? wtid0 : 6249;
    int n0 = wtid * 16;
    float b1t[4], b2t[4];
#pragma unroll
    for (int t = 0; t < 4; ++t) {
        b1t[t] = b1[t * 16 + p];
        b2t[t] = b2[t * 16 + p];
    }
    const half8* hrow = (const half8*)(h + (size_t)(n0 + p) * 64);
    half8 A0 = hrow[q], A1 = hrow[4 + q];
    floatx4 acc[4];
#pragma unroll
    for (int t = 0; t < 4; ++t) acc[t] = (floatx4){0.f, 0.f, 0.f, 0.f};
#pragma unroll
    for (int t = 0; t < 4; ++t) {
        acc[t] = __builtin_amdgcn_mfma_f32_16x16x32_f16(A0, WF1[t * 64 + lane],
                                                        acc[t], 0, 0, 0);
        acc[t] = __builtin_amdgcn_mfma_f32_16x16x32_f16(A1, WF1[(4 + t) * 64 + lane],
                                                        acc[t], 0, 0, 0);
    }
    float* T = Tbuf + (tid >> 6) * (16 * 68);
#pragma unroll
    for (int t = 0; t < 4; ++t) {
#pragma unroll
        for (int r = 0; r < 4; ++r)
            T[(q * 4 + r) * 68 + t * 16 + p] = fmaxf(acc[t][r] + b1t[t], 0.f);
    }
    const float* Tp = T + p * 68;
    float4 u0 = *(const float4*)(Tp + q * 8);
    float4 u1 = *(const float4*)(Tp + q * 8 + 4);
    float4 u2 = *(const float4*)(Tp + 32 + q * 8);
    float4 u3 = *(const float4*)(Tp + 32 + q * 8 + 4);
    half8 g0, g1;
    g0[0] = (_Float16)u0.x; g0[1] = (_Float16)u0.y;
    g0[2] = (_Float16)u0.z; g0[3] = (_Float16)u0.w;
    g0[4] = (_Float16)u1.x; g0[5] = (_Float16)u1.y;
    g0[6] = (_Float16)u1.z; g0[7] = (_Float16)u1.w;
    g1[0] = (_Float16)u2.x; g1[1] = (_Float16)u2.y;
    g1[2] = (_Float16)u2.z; g1[3] = (_Float16)u2.w;
    g1[4] = (_Float16)u3.x; g1[5] = (_Float16)u3.y;
    g1[6] = (_Float16)u3.z; g1[7] = (_Float16)u3.w;
#pragma unroll
    for (int t = 0; t < 4; ++t) acc[t] = (floatx4){0.f, 0.f, 0.f, 0.f};
#pragma unroll
    for (int t = 0; t < 4; ++t) {
        acc[t] = __builtin_amdgcn_mfma_f32_16x16x32_f16(g0, WF2[t * 64 + lane],
                                                        acc[t], 0, 0, 0);
        acc[t] = __builtin_amdgcn_mfma_f32_16x16x32_f16(g1, WF2[(4 + t) * 64 + lane],
                                                        acc[t], 0, 0, 0);
    }
    if (wtid0 < 6250) {
#pragma unroll
        for (int t = 0; t < 4; ++t) {
#pragma unroll
            for (int r = 0; r < 4; ++r)
                hh[(size_t)(n0 + q * 4 + r) * 64 + t * 16 + p] =
                    __float2half(fmaxf(acc[t][r] + b2t[t], 0.f));
        }
    }
}

// K4: pair decoder, folded weights: feat@dw1 = e1@(Ws+W1) + e2@(Ws+W2)
// + (e1.*e2)@Wp -> 6 sections, 24 MFMA/task. 782 blocks -> 6256 waves,
// exactly 2 tasks/wave.
__global__ void __launch_bounds__(512) k4_pair(const __half* __restrict__ hh,
                        const int* __restrict__ qidx,
                        const float* __restrict__ dw1, const float* __restrict__ db1,
                        const float* __restrict__ dw2, const float* __restrict__ db2,
                        float* __restrict__ out, int numWaves) {
    __shared__ half8 BF[1536];   // [s(6)][t(4)][lane(64)] -> 24 KB
    int tid = threadIdx.x;
    for (int f = tid; f < 1536; f += 512) {
        int lane = f & 63, st = f >> 6;
        int t = st & 3, s = st >> 2;         // s in [0,6)
        int sec = s >> 1, kh = s & 1;
        int q = lane >> 4, nl = lane & 15;
        int n = t * 16 + nl;
        int K0 = kh * 32 + q * 8;
        half8 hv;
#pragma unroll
        for (int j = 0; j < 8; ++j) {
            int k = K0 + j;
            float v;
            if (sec == 0)      v = dw1[k * 64 + n] + dw1[(128 + k) * 64 + n];
            else if (sec == 1) v = dw1[k * 64 + n] + dw1[(192 + k) * 64 + n];
            else               v = dw1[(64 + k) * 64 + n];
            hv[j] = (_Float16)v;
        }
        BF[f] = hv;
    }
    __syncthreads();
    int lane = tid & 63;
    int q = lane >> 4, nl = lane & 15;
    float db1t[4], dw2t[4];
#pragma unroll
    for (int t = 0; t < 4; ++t) {
        db1t[t] = db1[t * 16 + nl];
        dw2t[t] = dw2[t * 16 + nl];
    }
    float db2v = db2[0];
    int wid = (blockIdx.x * 512 + tid) >> 6;
    for (int task = wid; task < NPAIRS / 16; task += numWaves) {
        int p0 = task * 16;
        int i1 = qidx[p0 + nl];
        int i2 = qidx[NPAIRS + p0 + nl];
        const half8* r1 = (const half8*)(hh + (size_t)i1 * 64);
        const half8* r2 = (const half8*)(hh + (size_t)i2 * 64);
        half8 e1a = r1[q],     e1b = r1[4 + q];
        half8 e2a = r2[q],     e2b = r2[4 + q];
        half8 pA = e1a * e2a,  pB = e1b * e2b;    // v_pk_mul_f16
        floatx4 acc[4];
#pragma unroll
        for (int t = 0; t < 4; ++t) acc[t] = (floatx4){0.f, 0.f, 0.f, 0.f};

#define DO_STEP(S, AV)                                                        \
        _Pragma("unroll")                                                     \
        for (int t = 0; t < 4; ++t)                                           \
            acc[t] = __builtin_amdgcn_mfma_f32_16x16x32_f16(                  \
                (AV), BF[((S) * 4 + t) * 64 + lane], acc[t], 0, 0, 0);

        DO_STEP(0, e1a)  // e1 @ (Ws+W1), k 0..31
        DO_STEP(1, e1b)  // e1 @ (Ws+W1), k 32..63
        DO_STEP(2, e2a)  // e2 @ (Ws+W2)
        DO_STEP(3, e2b)
        DO_STEP(4, pA)   // (e1.*e2) @ Wp
        DO_STEP(5, pB)
#undef DO_STEP

        float part[4] = {0.f, 0.f, 0.f, 0.f};
#pragma unroll
        for (int t = 0; t < 4; ++t) {
#pragma unroll
            for (int r = 0; r < 4; ++r)
                part[r] = fmaf(fmaxf(acc[t][r] + db1t[t], 0.f), dw2t[t], part[r]);
        }
#pragma unroll
        for (int off = 1; off < 16; off <<= 1) {
#pragma unroll
            for (int r = 0; r < 4; ++r) part[r] += __shfl_xor(part[r], off, 64);
        }
        if (nl == 0) {
#pragma unroll
            for (int r = 0; r < 4; ++r) out[p0 + q * 4 + r] = part[r] + db2v;
        }
    }
}

extern "C" void kernel_launch(void* const* d_in, const int* in_sizes, int n_in,
                              void* d_out, int out_size, void* d_ws, size_t ws_size,
                              hipStream_t stream) {
    const float* x    = (const float*)d_in[0];   // [N,64]
    const int*   eidx = (const int*)d_in[1];     // [2,E]
    const int*   qidx = (const int*)d_in[3];     // [2,P]
    const float* w1   = (const float*)d_in[4];
    const float* b1   = (const float*)d_in[5];
    const float* w2   = (const float*)d_in[6];
    const float* b2   = (const float*)d_in[7];
    const float* dw1  = (const float*)d_in[8];   // [256,64]
    const float* db1  = (const float*)d_in[9];
    const float* dw2  = (const float*)d_in[10];  // [64]
    const float* db2  = (const float*)d_in[11];  // [1]
    float* out = (float*)d_out;                  // [P]

    // ws layout (48.41 MB total; 16B aligned):
    //   h0h (fp16) @ 0          : 12,800,000 B
    //   xh / hh    @ 12,800,000 : 12,800,000 B
    //   bucketArr  @ 25,600,000 :  8,808,448 B
    //   ovfList    @ 34,408,448 : 12,800,000 B
    //   rowptr     @ 47,208,448 :    400,000 B
    //   deg        @ 47,608,448 :    400,000 B
    //   matrix     @ 48,008,448 :    400,384 B
    //   bucketCnt  @ 48,408,832 :      1,564 B
    //   ovfCnt     @ 48,410,396 :          4 B
    char* ws = (char*)d_ws;
    __half* h0h       = (__half*)ws;
    __half* xh        = (__half*)(ws + 12800000);
    int*    bucketArr = (int*)(ws + 25600000);
    int2*   ovfList   = (int2*)(ws + 34408448);
    int*    rowptr    = (int*)(ws + 47208448);
    int*    deg       = (int*)(ws + 47608448);
    int*    matrix    = (int*)(ws + 48008448);
    int*    bucketCnt = (int*)(ws + 48408832);
    int*    ovfCnt    = (int*)(ws + 48410396);

    const int* src = eidx;
    const int* dst = eidx + N_EDGES;

    k0_fused<<<6250, 256, 0, stream>>>((const float4*)x, xh, dst, matrix, ovfCnt);
    p1b_scan<<<NB, 256, 0, stream>>>(matrix, bucketCnt);
    p1c_scatter<<<256, 1024, 0, stream>>>(src, dst, matrix, bucketArr,
                                          ovfCnt, ovfList);
    p2_build<<<NB, 256, 0, stream>>>(bucketArr, bucketCnt, rowptr, deg);
    k2_agg<<<3125, 256, 0, stream>>>(xh, h0h, deg, rowptr, bucketArr,
                                     ovfCnt, ovfList, x);
    k3_mfma<<<1563, 256, 0, stream>>>(h0h, xh, w1, b1, w2, b2);
    // K4: 782 blocks x 8 waves = 6256 waves -> exactly 2 tasks/wave
    k4_pair<<<782, 512, 0, stream>>>(xh, qidx, dw1, db1, dw2, db2, out, 6256);
}